// Round 17
// baseline (558.175 us; speedup 1.0000x reference)
//
#include <hip/hip_runtime.h>
#include <hip/hip_bf16.h>
#include <stdint.h>

#define S_LEN  2048
#define NHEADS 16
#define D_NOPE 128
#define D_ROPE 64
#define D_V    128
#define D_Q    192
#define ITOPK  512

static constexpr float ATT_SCALE = 0.07216878364870322f;   // 192^-0.5
static constexpr float ISC4      = 0.04419417382415922f;   // (32^-0.5)/4
static constexpr float RMS_EPS   = 1e-6f;

typedef __bf16 bf16x8 __attribute__((ext_vector_type(8)));
typedef float  f32x4  __attribute__((ext_vector_type(4)));

__device__ __forceinline__ float b2f(unsigned short u) {
    union { unsigned int i; float f; } x; x.i = ((unsigned int)u) << 16; return x.f;
}
__device__ __forceinline__ unsigned short f2b(float f) {   // RNE
    union { float f; unsigned int i; } x; x.f = f;
    unsigned int lsb = (x.i >> 16) & 1;
    x.i += 0x7fffu + lsb;
    return (unsigned short)(x.i >> 16);
}

// async global->LDS, 16B per lane; LDS dest must be wave-uniform base + lane*16
__device__ __forceinline__ void gload16(const unsigned short* g, unsigned short* l)
{
    __builtin_amdgcn_global_load_lds(
        (const __attribute__((address_space(1))) unsigned int*)g,
        (__attribute__((address_space(3))) unsigned int*)l, 16, 0, 0);
}

// ---------------- fused f32 -> bf16 casts (6 segments, TOTAL 4,882,432 float4) ----------------
__global__ __launch_bounds__(256)
void cast_all(const float* __restrict__ x,    const float* __restrict__ qaw_,
              const float* __restrict__ kvaw_, const float* __restrict__ qbw_,
              const float* __restrict__ kvbw_, const float* __restrict__ ow_,
              unsigned short* __restrict__ xb,   unsigned short* __restrict__ wcat,
              unsigned short* __restrict__ qbw,  unsigned short* __restrict__ kvbw,
              unsigned short* __restrict__ owb)
{
    int i = blockIdx.x * 256 + threadIdx.x;   // float4 index
    const float* s; unsigned short* d; int off;
    if      (i < 1048576) { s = x;     d = xb;              off = 0;       }
    else if (i < 1835008) { s = qaw_;  d = wcat;            off = 1048576; }
    else if (i < 2129920) { s = kvaw_; d = wcat + 3145728;  off = 1835008; }
    else if (i < 3309568) { s = qbw_;  d = qbw;             off = 2129920; }
    else if (i < 3833856) { s = kvbw_; d = kvbw;            off = 3309568; }
    else if (i < 4882432) { s = ow_;   d = owb;             off = 3833856; }
    else return;
    int j = i - off;
    float4 v = ((const float4*)s)[j];
    ushort4 o;
    o.x = f2b(v.x); o.y = f2b(v.y); o.z = f2b(v.z); o.w = f2b(v.w);
    ((ushort4*)d)[j] = o;
}

// ---------------- f32 VALU GEMM, BK=16, dual-B (indexer iq|ik; ROUND-10-EXACT math) ----
__global__ __launch_bounds__(256)
void gemm_f32_iqik(const float* __restrict__ A, int lda,
                   const float* __restrict__ Bq, const float* __restrict__ Bk,
                   float* __restrict__ C, int M, float alpha, int kChunk)
{
    __shared__ float As[16][132];
    __shared__ float Bs[16][132];
    const int row0 = blockIdx.y * 128;
    const int col0 = blockIdx.x * 128;
    const int t  = threadIdx.x;
    const int tx = t & 15, ty = t >> 4;
    const int kStart = blockIdx.z * kChunk;
    C += (size_t)blockIdx.z * M * 256;

    float acc[8][8] = {};

    for (int k0 = kStart; k0 < kStart + kChunk; k0 += 16) {
#pragma unroll
        for (int i = 0; i < 2; i++) {
            int f = t + i * 256;
            int r = f >> 2;
            int kq = (f & 3) << 2;
            int gr = row0 + r;
            float4 va = make_float4(0.f, 0.f, 0.f, 0.f);
            if (gr < M) va = *(const float4*)(A + (size_t)gr * lda + k0 + kq);
            As[kq + 0][r] = va.x; As[kq + 1][r] = va.y;
            As[kq + 2][r] = va.z; As[kq + 3][r] = va.w;
            int gc = col0 + r;    // 0..255
            const float* bp = (gc < 128) ? (Bq + (size_t)gc * 2048)
                                         : (Bk + (size_t)(gc - 128) * 2048);
            float4 vb = *(const float4*)(bp + k0 + kq);
            Bs[kq + 0][r] = vb.x; Bs[kq + 1][r] = vb.y;
            Bs[kq + 2][r] = vb.z; Bs[kq + 3][r] = vb.w;
        }
        __syncthreads();
#pragma unroll
        for (int kk = 0; kk < 16; kk++) {
            float4 A0 = *(const float4*)&As[kk][ty * 8];
            float4 A1 = *(const float4*)&As[kk][ty * 8 + 4];
            float4 B0 = *(const float4*)&Bs[kk][tx * 8];
            float4 B1 = *(const float4*)&Bs[kk][tx * 8 + 4];
            float a[8] = {A0.x, A0.y, A0.z, A0.w, A1.x, A1.y, A1.z, A1.w};
            float b[8] = {B0.x, B0.y, B0.z, B0.w, B1.x, B1.y, B1.z, B1.w};
#pragma unroll
            for (int i = 0; i < 8; i++)
#pragma unroll
                for (int j = 0; j < 8; j++)
                    acc[i][j] = fmaf(a[i], b[j], acc[i][j]);
        }
        __syncthreads();
    }

#pragma unroll
    for (int i = 0; i < 8; i++) {
        int r = row0 + ty * 8 + i;
        if (r >= M) continue;
#pragma unroll
        for (int j = 0; j < 8; j++) {
            int c = col0 + tx * 8 + j;
            C[(size_t)r * 256 + c] = acc[i][j] * alpha;
        }
    }
}

// ---------------- f32 VALU GEMM, BK=16, strided A/B (isc; ROUND-10 EXACT) ----
__global__ __launch_bounds__(256)
void gemm_f32_nt(const float* __restrict__ A, int lda,
                 const float* __restrict__ B, int ldb,
                 float* __restrict__ C, int M, int N, float alpha, int kChunk)
{
    __shared__ float As[16][132];
    __shared__ float Bs[16][132];
    const int row0 = blockIdx.y * 128;
    const int col0 = blockIdx.x * 128;
    const int t  = threadIdx.x;
    const int tx = t & 15, ty = t >> 4;
    const int kStart = blockIdx.z * kChunk;
    C += (size_t)blockIdx.z * M * N;

    float acc[8][8] = {};

    for (int k0 = kStart; k0 < kStart + kChunk; k0 += 16) {
#pragma unroll
        for (int i = 0; i < 2; i++) {
            int f = t + i * 256;
            int r = f >> 2;
            int kq = (f & 3) << 2;
            int gr = row0 + r;
            float4 va = make_float4(0.f, 0.f, 0.f, 0.f);
            if (gr < M) va = *(const float4*)(A + (size_t)gr * lda + k0 + kq);
            As[kq + 0][r] = va.x; As[kq + 1][r] = va.y;
            As[kq + 2][r] = va.z; As[kq + 3][r] = va.w;
            int gc = col0 + r;
            float4 vb = make_float4(0.f, 0.f, 0.f, 0.f);
            if (gc < N) vb = *(const float4*)(B + (size_t)gc * ldb + k0 + kq);
            Bs[kq + 0][r] = vb.x; Bs[kq + 1][r] = vb.y;
            Bs[kq + 2][r] = vb.z; Bs[kq + 3][r] = vb.w;
        }
        __syncthreads();
#pragma unroll
        for (int kk = 0; kk < 16; kk++) {
            float4 A0 = *(const float4*)&As[kk][ty * 8];
            float4 A1 = *(const float4*)&As[kk][ty * 8 + 4];
            float4 B0 = *(const float4*)&Bs[kk][tx * 8];
            float4 B1 = *(const float4*)&Bs[kk][tx * 8 + 4];
            float a[8] = {A0.x, A0.y, A0.z, A0.w, A1.x, A1.y, A1.z, A1.w};
            float b[8] = {B0.x, B0.y, B0.z, B0.w, B1.x, B1.y, B1.z, B1.w};
#pragma unroll
            for (int i = 0; i < 8; i++)
#pragma unroll
                for (int j = 0; j < 8; j++)
                    acc[i][j] = fmaf(a[i], b[j], acc[i][j]);
        }
        __syncthreads();
    }

#pragma unroll
    for (int i = 0; i < 8; i++) {
        int r = row0 + ty * 8 + i;
        if (r >= M) continue;
#pragma unroll
        for (int j = 0; j < 8; j++) {
            int c = col0 + tx * 8 + j;
            if (c >= N) continue;
            C[(size_t)r * N + c] = acc[i][j] * alpha;
        }
    }
}

// ---------------- reduce P split-K partials (in-place over slab 0 safe) ----------------
__global__ __launch_bounds__(256)
void reduceN_k(const float* __restrict__ p, float* __restrict__ out, int n4, int parts)
{
    int i = blockIdx.x * 256 + threadIdx.x;
    if (i < n4) {
        const float4* a = (const float4*)p;
        float4 o = a[i];
        for (int z = 1; z < parts; z++) {
            float4 r = a[i + (size_t)z * n4];
            o.x += r.x; o.y += r.y; o.z += r.z; o.w += r.w;
        }
        ((float4*)out)[i] = o;
    }
}

// ---------------- bf16 MFMA GEMM, strided + per-z stepped ----------------
template<bool OUTBF16>
__global__ __launch_bounds__(256)
void gemm_bf16_nt(const unsigned short* __restrict__ A, int lda, int aStep,
                  const unsigned short* __restrict__ B, int ldb, int bStep,
                  void* __restrict__ Cv, int ldc, int cStep,
                  int M, int N, int K, float alpha)
{
    __shared__ unsigned short As[128 * 32];
    __shared__ unsigned short Bs[128 * 32];
    A += (size_t)blockIdx.z * aStep;
    B += (size_t)blockIdx.z * bStep;
    unsigned short* Cb = (unsigned short*)Cv + (size_t)blockIdx.z * cStep;
    float*          Cf = (float*)Cv          + (size_t)blockIdx.z * cStep;

    const int t = threadIdx.x;
    const int row0 = blockIdx.y * 128, col0 = blockIdx.x * 128;
    const int w = t >> 6, l = t & 63;
    const int wr = (w >> 1) * 64, wc = (w & 1) * 64;
    const int fr = l & 15, fk = l >> 4;

    f32x4 acc[4][4] = {};

    const int sr = t >> 2, ss = t & 3;

    for (int k0 = 0; k0 < K; k0 += 32) {
#pragma unroll
        for (int c = 0; c < 2; c++) {
            int r  = sr + c * 64;
            int ga = min(row0 + r, M - 1);
            int gb = min(col0 + r, N - 1);
            gload16(A + (size_t)ga * lda + k0 + ss * 8, As + (c * 256 + t) * 8);
            gload16(B + (size_t)gb * ldb + k0 + ss * 8, Bs + (c * 256 + t) * 8);
        }
        __syncthreads();

        bf16x8 af[4], bfr[4];
#pragma unroll
        for (int mi = 0; mi < 4; mi++) {
            int ra = wr + mi * 16 + fr;
            af[mi] = *(const bf16x8*)((const char*)As + ra * 64 + fk * 16);
        }
#pragma unroll
        for (int nj = 0; nj < 4; nj++) {
            int rb = wc + nj * 16 + fr;
            bfr[nj] = *(const bf16x8*)((const char*)Bs + rb * 64 + fk * 16);
        }
#pragma unroll
        for (int mi = 0; mi < 4; mi++)
#pragma unroll
            for (int nj = 0; nj < 4; nj++)
                acc[mi][nj] = __builtin_amdgcn_mfma_f32_16x16x32_bf16(
                                  af[mi], bfr[nj], acc[mi][nj], 0, 0, 0);
        __syncthreads();
    }

    // C/D: col = lane&15, row = (lane>>4)*4 + reg
#pragma unroll
    for (int mi = 0; mi < 4; mi++)
#pragma unroll
        for (int nj = 0; nj < 4; nj++)
#pragma unroll
            for (int rg = 0; rg < 4; rg++) {
                int rr = row0 + wr + mi * 16 + fk * 4 + rg;
                int cc = col0 + wc + nj * 16 + fr;
                if (rr < M && cc < N) {
                    float v = acc[mi][nj][rg] * alpha;
                    if constexpr (OUTBF16) Cb[(size_t)rr * ldc + cc] = f2b(v);
                    else                   Cf[(size_t)rr * ldc + cc] = v;
                }
            }
}

// ---------------- RMSNorm bf16 in-place (strided rows) ----------------
__global__ __launch_bounds__(256)
void rms_bf16_inplace(unsigned short* x, const float* __restrict__ w, int n, int stride)
{
    __shared__ float red[256];
    const int row = blockIdx.x, t = threadIdx.x;
    unsigned short* ip = x + (size_t)row * stride;
    float ss = 0.f;
    for (int i = t; i < n; i += 256) { float v = b2f(ip[i]); ss = fmaf(v, v, ss); }
    red[t] = ss; __syncthreads();
    for (int s2 = 128; s2; s2 >>= 1) { if (t < s2) red[t] += red[t + s2]; __syncthreads(); }
    float rs = rsqrtf(red[0] / (float)n + RMS_EPS);
    for (int i = t; i < n; i += 256) ip[i] = f2b(b2f(ip[i]) * rs * w[i]);
}

// ---------------- fused RMS(ckv) + RoPE(k_pe): xa[row][1536..2111] -> klat[row][0..575] ----
__global__ __launch_bounds__(256)
void rmsrope_klat(const unsigned short* __restrict__ xa, const float* __restrict__ w,
                  const float* __restrict__ cosb, const float* __restrict__ sinb,
                  unsigned short* __restrict__ klat)
{
    __shared__ float red[256];
    const int row = blockIdx.x, t = threadIdx.x;
    const unsigned short* ip = xa + (size_t)row * 2112 + 1536;   // 512 ckv | 64 kpe
    float v0 = b2f(ip[t]), v1 = b2f(ip[t + 256]);
    red[t] = v0 * v0 + v1 * v1; __syncthreads();
    for (int s2 = 128; s2; s2 >>= 1) { if (t < s2) red[t] += red[t + s2]; __syncthreads(); }
    float rs = rsqrtf(red[0] / 512.f + RMS_EPS);
    unsigned short* op = klat + (size_t)row * 576;
    op[t]       = f2b(v0 * rs * w[t]);
    op[t + 256] = f2b(v1 * rs * w[t + 256]);
    if (t < 32) {
        int d = t;
        float x1 = b2f(ip[512 + d]), x2 = b2f(ip[512 + d + 32]);
        const float* cr = cosb + (size_t)row * D_ROPE;
        const float* sr = sinb + (size_t)row * D_ROPE;
        op[512 + d]      = f2b(x1 * cr[d]      - x2 * sr[d]);
        op[512 + d + 32] = f2b(x2 * cr[d + 32] + x1 * sr[d + 32]);
    }
}

// ---------------- RoPE q_pe: qbuf[S][16][192] dims 128.. -> qec[S][16][576] dims 512.. ----
__global__ __launch_bounds__(256)
void rope_q_k(const unsigned short* __restrict__ qbuf, const float* __restrict__ cosb,
              const float* __restrict__ sinb, unsigned short* __restrict__ qec)
{
    int idx = blockIdx.x * 256 + threadIdx.x;  // S*16*32
    int s = idx >> 9, h = (idx >> 5) & 15, d = idx & 31;
    const unsigned short* qp = qbuf + ((size_t)s * NHEADS + h) * D_Q + D_NOPE;
    float x1 = b2f(qp[d]), x2 = b2f(qp[d + 32]);
    const float* cr = cosb + (size_t)s * D_ROPE;
    const float* sr = sinb + (size_t)s * D_ROPE;
    unsigned short* op = qec + ((size_t)s * NHEADS + h) * 576 + 512;
    op[d]      = f2b(x1 * cr[d]      - x2 * sr[d]);
    op[d + 32] = f2b(x2 * cr[d + 32] + x1 * sr[d + 32]);
}

// ---------------- transpose W_kb (k_nope half): Wkt[h][c<512][d<128] ----------------
__global__ __launch_bounds__(256)
void wkt_k(const unsigned short* __restrict__ kvbw, unsigned short* __restrict__ wkt)
{
    __shared__ unsigned short tile[32][520];
    const int h = blockIdx.x, dc = blockIdx.y, t = threadIdx.x;
    for (int i = t; i < 32 * 64; i += 256) {
        int d = i >> 6, c8 = (i & 63) * 8;
        uint4 v = *(const uint4*)(kvbw + ((size_t)(h * 256 + dc * 32 + d)) * 512 + c8);
        *(uint4*)&tile[d][c8] = v;
    }
    __syncthreads();
    for (int i = t; i < 512 * 4; i += 256) {
        int c = i >> 2, d8 = (i & 3) * 8;
        unsigned short tmp[8];
#pragma unroll
        for (int j = 0; j < 8; j++) tmp[j] = tile[d8 + j][c];
        *(uint4*)(wkt + ((size_t)h * 512 + c) * 128 + dc * 32 + d8) = *(uint4*)tmp;
    }
}

// ---------------- ckv column means (empty-mask fallback) ----------------
__global__ __launch_bounds__(256)
void ckvsum_k(const unsigned short* __restrict__ klat, float* __restrict__ part)
{
    const int b = blockIdx.x, t = threadIdx.x;
    float s0 = 0.f, s1 = 0.f;
    for (int r = 0; r < 128; r++) {
        const unsigned short* row = klat + (size_t)(b * 128 + r) * 576;
        s0 += b2f(row[t]); s1 += b2f(row[t + 256]);
    }
    part[b * 512 + t] = s0; part[b * 512 + t + 256] = s1;
}
__global__ __launch_bounds__(256)
void ckvmean_k(const float* __restrict__ part, float* __restrict__ mean)
{
    int t = blockIdx.x * 256 + threadIdx.x;
    if (t < 512) {
        float s = 0.f;
        for (int b = 0; b < 16; b++) s += part[b * 512 + t];
        mean[t] = s * (1.f / 2048.f);
    }
}

// ---------------- per-row top-512 -> bitmask, 4-pass byte radix-select ----------------
__global__ __launch_bounds__(256)
void topk_mask_k(const float* __restrict__ iscores, uint32_t* __restrict__ mask)
{
    const int q = blockIdx.x, t = threadIdx.x;
    const int w = t >> 6, l = t & 63;
    __shared__ uint32_t u[S_LEN];
    __shared__ int hist4[4][256];
    __shared__ int sfx[257];
    __shared__ int wtot[4];
    __shared__ uint32_t mw[64];
    __shared__ int sh_b, sh_R;

    for (int i = t; i < S_LEN; i += 256) {
        uint32_t b = __float_as_uint(iscores[(size_t)q * S_LEN + i]);
        u[i] = (b & 0x80000000u) ? ~b : (b | 0x80000000u);  // order-preserving map
    }
    if (t < 64) mw[t] = 0u;

    uint32_t prefix = 0;
    int R = ITOPK;
#pragma unroll 1
    for (int shift = 24; shift >= 0; shift -= 8) {
        hist4[0][t] = 0; hist4[1][t] = 0; hist4[2][t] = 0; hist4[3][t] = 0;
        __syncthreads();
        uint32_t pmask = (shift == 24) ? 0u : (0xFFFFFFFFu << (shift + 8));
        for (int i = t; i < S_LEN; i += 256) {
            uint32_t v = u[i];
            if ((v & pmask) == prefix)
                atomicAdd(&hist4[w][(v >> shift) & 255], 1);
        }
        __syncthreads();
        int x = hist4[0][255 - t] + hist4[1][255 - t] + hist4[2][255 - t] + hist4[3][255 - t];
#pragma unroll
        for (int d = 1; d < 64; d <<= 1) {
            int y = __shfl_up(x, d);
            if (l >= d) x += y;
        }
        if (l == 63) wtot[w] = x;
        __syncthreads();
        for (int ww = 0; ww < w; ww++) x += wtot[ww];
        sfx[255 - t] = x;
        if (t == 0) sfx[256] = 0;
        __syncthreads();
        if (sfx[t] >= R && sfx[t + 1] < R) { sh_b = t; sh_R = R - sfx[t + 1]; }
        __syncthreads();
        prefix |= (uint32_t)sh_b << shift;
        R = sh_R;
        __syncthreads();
    }
    const uint32_t T = prefix;
    const int need = R;

    for (int i = t; i < S_LEN; i += 256) {
        uint32_t v = u[i];
        bool sel = v > T;
        if (!sel && v == T) {
            int rank = 0;
            for (int j = 0; j < i; j++) rank += (u[j] == T) ? 1 : 0;
            sel = rank < need;
        }
        if (sel) atomicOr(&mw[i >> 5], 1u << (i & 31));
    }
    __syncthreads();
    if (t < 64) mask[(size_t)q * 64 + t] = mw[t];
}

// ---------------- absorbed-MLA sparse attention: one block per q, all 16 heads ----
// Quarter-lat CT tile (~28.9KB LDS -> 5 blocks/CU, was 39.4KB/4). Same staged bytes,
// same per-register MFMA sequence -> bit-identical ov vs round 16.
__global__ __launch_bounds__(256, 5)
void attn_lat_k(const unsigned short* __restrict__ qec,
                const unsigned short* __restrict__ klat,
                const uint32_t* __restrict__ mask,
                const float* __restrict__ ckvmean,
                unsigned short* __restrict__ ov)
{
    const int qi = blockIdx.x, t = threadIdx.x;
    const int w = t >> 6, l = t & 63;
    const int c16 = l & 15, g = l >> 4;

    __shared__ unsigned short kl[512];
    __shared__ uint32_t wds[64];
    __shared__ int pfx[65];
    __shared__ float wred[4][16];
    __shared__ float linv[16];
    __shared__ unsigned short PB[16][520];   // P (unnormalized exp) bf16
    __shared__ unsigned short CT[128][40];   // ckv_sel^T quarter-lat tile, swizzled cols

    kl[t] = 0; kl[t + 256] = 0;
    if (t < 64) {
        uint32_t wd = mask[(size_t)qi * 64 + t];
        int rem = qi - t * 32;                 // causal
        if (rem < 0) wd = 0u;
        else if (rem < 31) wd &= ((2u << rem) - 1u);
        wds[t] = wd;
        pfx[t] = __popc(wd);
    }
    __syncthreads();
    if (t == 0) {
        int s = 0;
        for (int i = 0; i < 64; i++) { int cc = pfx[i]; pfx[i] = s; s += cc; }
        pfx[64] = s;
    }
    __syncthreads();
    const int nv = pfx[64];

    if (nv == 0) {   // uniform softmax over all keys == mean(ckv) in latent space
        for (int i = t; i < 16 * 512; i += 256) {
            int h = i >> 9, c = i & 511;
            ov[((size_t)qi * 16 + h) * 512 + c] = f2b(ckvmean[c]);
        }
        return;
    }

    if (t < 64) {
        int pos = pfx[t];
        uint32_t wd = wds[t];
        while (wd) { int b = __ffs(wd) - 1; wd &= wd - 1; kl[pos++] = (unsigned short)(t * 32 + b); }
    }
    __syncthreads();

    const int ntile = (nv + 63) >> 6;   // 64-key macro tiles (4 waves x 16)

    // ---- scores: S[h=16][key] = Qec[16x576] @ Klat_sel^T via MFMA ----
    f32x4 acc[8] = {};
    uint32_t kb[8];
#pragma unroll
    for (int tt = 0; tt < 8; tt++)
        kb[tt] = (uint32_t)kl[tt * 64 + w * 16 + c16] * 1152u;

    const unsigned short* qrow = qec + (size_t)qi * (16 * 576);
#pragma unroll 2
    for (int ks = 0; ks < 18; ks++) {
        bf16x8 af = *(const bf16x8*)(qrow + c16 * 576 + ks * 32 + g * 8);
#pragma unroll
        for (int tt = 0; tt < 8; tt++) {
            if (tt < ntile) {
                bf16x8 bf = *(const bf16x8*)((const char*)klat + (kb[tt] + (uint32_t)(ks * 64 + g * 16)));
                acc[tt] = __builtin_amdgcn_mfma_f32_16x16x32_bf16(af, bf, acc[tt], 0, 0, 0);
            }
        }
    }

    // scale + pad-mask + per-head max
    float m4[4];
#pragma unroll
    for (int r = 0; r < 4; r++) {
        float mm = -1e30f;
#pragma unroll
        for (int tt = 0; tt < 8; tt++) {
            if (tt < ntile) {
                int kp = tt * 64 + w * 16 + c16;
                float s = (kp < nv) ? acc[tt][r] * ATT_SCALE : -1e30f;
                acc[tt][r] = s;
                mm = fmaxf(mm, s);
            }
        }
#pragma unroll
        for (int o = 8; o; o >>= 1) mm = fmaxf(mm, __shfl_xor(mm, o));
        m4[r] = mm;
    }
    if (c16 == 0) {
#pragma unroll
        for (int r = 0; r < 4; r++) wred[w][g * 4 + r] = m4[r];
    }
    __syncthreads();
#pragma unroll
    for (int r = 0; r < 4; r++) {
        int h = g * 4 + r;
        m4[r] = fmaxf(fmaxf(wred[0][h], wred[1][h]), fmaxf(wred[2][h], wred[3][h]));
    }
    __syncthreads();   // wred reused for sums

    float s4[4] = {0.f, 0.f, 0.f, 0.f};
#pragma unroll
    for (int tt = 0; tt < 8; tt++) {
        if (tt < ntile) {
            int kp = tt * 64 + w * 16 + c16;
#pragma unroll
            for (int r = 0; r < 4; r++) {
                float e = __expf(acc[tt][r] - m4[r]);   // pad keys -> 0
                s4[r] += e;
                PB[g * 4 + r][kp] = f2b(e);
            }
        }
    }
#pragma unroll
    for (int r = 0; r < 4; r++) {
        float ss = s4[r];
#pragma unroll
        for (int o = 8; o; o >>= 1) ss += __shfl_xor(ss, o);
        s4[r] = ss;
    }
    if (c16 == 0) {
#pragma unroll
        for (int r = 0; r < 4; r++) wred[w][g * 4 + r] = s4[r];
    }
    __syncthreads();
    if (t < 16) linv[t] = 1.f / (wred[0][t] + wred[1][t] + wred[2][t] + wred[3][t]);

    // ---- PV: ov[16][512] = P[16 x nv] @ ckv_sel[nv x 512], quarter-lat CT ----
    // Thread t stages keys (2k2, 2k2+1) x 8 lats (lg*8..) per (ht, 32-key chunk).
    // Write pair-col = k2 ^ ((la>>4)&3)<<2 (la = lg*8+j); read col = (g ^ ((rowh>>4)&3))*8.
    f32x4 pv[8] = {};
    const int nkc = (nv + 31) >> 5;
    const int k2 = t >> 4, lg = t & 15;
    const int cp = (k2 ^ (((lg >> 1) & 3) << 2)) * 2;   // u16 col of this thread's key pair
    uint4 stg[2];

#define LOADKEYS(HT, KC) do { \
        uint32_t kb0 = (uint32_t)kl[(KC) * 32 + 2 * k2] * 1152u; \
        uint32_t kb1 = (uint32_t)kl[(KC) * 32 + 2 * k2 + 1] * 1152u; \
        stg[0] = *(const uint4*)((const char*)klat + kb0 + (HT) * 256 + lg * 16); \
        stg[1] = *(const uint4*)((const char*)klat + kb1 + (HT) * 256 + lg * 16); \
    } while (0)

    LOADKEYS(0, 0);
#pragma unroll
    for (int ht = 0; ht < 4; ht++) {
        for (int kc = 0; kc < nkc; kc++) {
            __syncthreads();     // prev MFMA done with CT; first iter publishes PB/linv
            {
                uint4 a4 = stg[0], b4 = stg[1];
                int la = lg * 8;
                *(uint32_t*)&CT[la + 0][cp] = (a4.x & 0xFFFFu) | (b4.x << 16);
                *(uint32_t*)&CT[la + 1][cp] = (a4.x >> 16) | (b4.x & 0xFFFF0000u);
                *(uint32_t*)&CT[la + 2][cp] = (a4.y & 0xFFFFu) | (b4.y << 16);
                *(uint32_t*)&CT[la + 3][cp] = (a4.y >> 16) | (b4.y & 0xFFFF0000u);
                *(uint32_t*)&CT[la + 4][cp] = (a4.z & 0xFFFFu) | (b4.z << 16);
                *(uint32_t*)&CT[la + 5][cp] = (a4.z >> 16) | (b4.z & 0xFFFF0000u);
                *(uint32_t*)&CT[la + 6][cp] = (a4.w & 0xFFFFu) | (b4.w << 16);
                *(uint32_t*)&CT[la + 7][cp] = (a4.w >> 16) | (b4.w & 0xFFFF0000u);
            }
            if (kc + 1 < nkc) LOADKEYS(ht, kc + 1);      // fly under this chunk's MFMAs
            else if (ht < 3) LOADKEYS(ht + 1, 0);
            __syncthreads();
            bf16x8 pa = *(const bf16x8*)(&PB[c16][kc * 32 + g * 8]);
            __builtin_amdgcn_s_setprio(1);
#pragma unroll
            for (int nt = 0; nt < 2; nt++) {
                int rowh = w * 32 + nt * 16 + c16;
                int rsh = (rowh >> 4) & 3;               // = (w*2+nt)&3
                bf16x8 cb = *(const bf16x8*)(&CT[rowh][(g ^ rsh) * 8]);
                pv[ht * 2 + nt] = __builtin_amdgcn_mfma_f32_16x16x32_bf16(
                                      pa, cb, pv[ht * 2 + nt], 0, 0, 0);
            }
            __builtin_amdgcn_s_setprio(0);
        }
    }
#undef LOADKEYS

#pragma unroll
    for (int ht = 0; ht < 4; ht++)
#pragma unroll
        for (int nt = 0; nt < 2; nt++)
#pragma unroll
            for (int r = 0; r < 4; r++) {
                int h = g * 4 + r;
                int lat = ht * 128 + w * 32 + nt * 16 + c16;
                ov[((size_t)qi * 16 + h) * 512 + lat] = f2b(pv[ht * 2 + nt][r] * linv[h]);
            }
}

// ---------------- launch ----------------
extern "C" void kernel_launch(void* const* d_in, const int* in_sizes, int n_in,
                              void* d_out, int out_size, void* d_ws, size_t ws_size,
                              hipStream_t stream)
{
    const float* x       = (const float*)d_in[0];
    const float* cosb    = (const float*)d_in[1];
    const float* sinb    = (const float*)d_in[2];
    const float* q_a_w   = (const float*)d_in[3];
    const float* q_a_nw  = (const float*)d_in[4];
    const float* q_b_w   = (const float*)d_in[5];
    const float* kv_a_w  = (const float*)d_in[6];
    const float* kv_a_nw = (const float*)d_in[7];
    const float* kv_b_w  = (const float*)d_in[8];
    const float* o_w     = (const float*)d_in[9];
    const float* idx_q_w = (const float*)d_in[10];
    const float* idx_k_w = (const float*)d_in[11];
    (void)in_sizes; (void)n_in; (void)out_size; (void)ws_size;

    typedef unsigned short u16;
    char* ws = (char*)d_ws;
    // region A (overlaid by qec after step 5 — qec LIVE through step 8)
    u16*      xb   = (u16*)(ws + 0);          //  8,388,608 x bf16
    u16*      wcat = (u16*)(ws + 8388608);    //  8,650,752 [2112][2048] q_a_w|kv_a_w bf16
    u16*      qbw  = (u16*)(ws + 17039360);   //  9,437,184 q_b_w bf16
    u16*      xa   = (u16*)(ws + 26476544);   //  8,650,752 [2048][2112] q_a|ckv|kpe bf16
    u16*      qec  = (u16*)(ws + 0);          // 37,748,736 [S][16][576] (overlay, steps 5-8)
    // region B (33.5MB): wkt -> ipc/iqik/isc -> ov
    u16*      wkt  = (u16*)(ws + 37748736);   //  2,097,152 W_kb^T per head [steps 4-5]
    float*    ipc  = (float*)(ws + 37748736); // 16,777,216 idx partials x8 [step 7]
    float*    iqik = (float*)(ws + 37748736); //  2,097,152 [2048][256] (in-place reduce, slab 0)
    float*    isc  = (float*)(ws + 39845888); // 16,777,216 iscores (overlaps dead ipc slabs 1-7)
    u16*      ov   = (u16*)(ws + 37748736);   // 33,554,432 [S][16][512] (overlay, step 8+)
    // region C
    u16*      qbuf = (u16*)(ws + 71303168);   // 12,582,912 q bf16 (dead after step 5)
    u16*      aoutb= (u16*)(ws + 71303168);   //  8,388,608 attn out (overlay, step 9+)
    u16*      klat = (u16*)(ws + 83886080);   //  2,359,296 [S][576] latent K
    u16*      kvbw = (u16*)(ws + 86245376);   //  4,194,304 kv_b_w bf16
    u16*      owb  = (u16*)(ws + 90439680);   //  8,388,608 o_w bf16
    uint32_t* mask = (uint32_t*)(ws + 98828288); // 524,288
    float*    ckvm = (float*)(ws + 99352576); //      2,048
    float*    cprt = (float*)(ws + 99354624); //     32,768  (end 99,387,392)

    dim3 blk(256);

    // 1. all casts fused — grid covers 4,882,432 float4 exactly
    cast_all<<<19072, blk, 0, stream>>>(x, q_a_w, kv_a_w, q_b_w, kv_b_w, o_w,
                                        xb, wcat, qbw, kvbw, owb);

    // 2. fused low-rank projection: xa[2048][2112] = xb @ wcat^T
    gemm_bf16_nt<true ><<<dim3(17, 16), blk, 0, stream>>>(xb, 2048, 0, wcat, 2048, 0,
                                                          xa, 2112, 0, 2048, 2112, 2048, 1.f);
    // 3. norms + k rope (q_a in-place; ckv+kpe -> klat)
    rms_bf16_inplace<<<2048, blk, 0, stream>>>(xa, q_a_nw, 1536, 2112);
    rmsrope_klat<<<2048, blk, 0, stream>>>(xa, kv_a_nw, cosb, sinb, klat);

    // 4. q_b projection + W_kb transpose
    gemm_bf16_nt<true ><<<dim3(24, 16), blk, 0, stream>>>(xa, 2112, 0, qbw, 1536, 0,
                                                          qbuf, 3072, 0, 2048, 3072, 1536, 1.f);
    wkt_k<<<dim3(16, 4), blk, 0, stream>>>(kvbw, wkt);

    // 5. absorbed q: qec[:,:,0:512] = q_nope @ W_kb^T; qec[:,:,512:576] = rope(q_pe)
    gemm_bf16_nt<true ><<<dim3(4, 16, 16), blk, 0, stream>>>(qbuf, 3072, 192, wkt, 128, 512 * 128,
                                                             qec, 9216, 576, 2048, 512, 128, 1.f);
    rope_q_k<<<4096, blk, 0, stream>>>(qbuf, cosb, sinb, qec);

    // 6. latent mean (fallback rows)
    ckvsum_k<<<16, blk, 0, stream>>>(klat, cprt);
    ckvmean_k<<<2, blk, 0, stream>>>(cprt, ckvm);

    // 7. indexer — ROUND-10-EXACT math (BK=16, kChunk=256, z=8); dual-B
    gemm_f32_iqik<<<dim3(2, 16, 8), blk, 0, stream>>>(x, 2048, idx_q_w, idx_k_w,
                                                      ipc, 2048, 1.f, 256);
    reduceN_k<<<512, blk, 0, stream>>>(ipc, iqik, 131072, 8);
    gemm_f32_nt<<<dim3(16, 16, 1), blk, 0, stream>>>(iqik, 256, iqik + 128, 256,
                                                     isc, 2048, 2048, ISC4, 128);
    topk_mask_k<<<2048, blk, 0, stream>>>(isc, mask);

    // 8. absorbed sparse attention (natural qi order, 5 blocks/CU)
    attn_lat_k<<<2048, blk, 0, stream>>>(qec, klat, mask, ckvm, ov);

    // 9. un-absorb values: aout[q][h*128+d] = ov[q][h] . W_vb[h][d]
    gemm_bf16_nt<true ><<<dim3(1, 16, 16), blk, 0, stream>>>(ov, 8192, 512,
                                                             kvbw + 128 * 512, 512, 256 * 512,
                                                             aoutb, 2048, 128, 2048, 128, 512, 1.f);
    // 10. output projection (f32 out)
    gemm_bf16_nt<false><<<dim3(16, 16), blk, 0, stream>>>(aoutb, 2048, 0, owb, 2048, 0,
                                                          (float*)d_out, 2048, 0, 2048, 2048, 2048, 1.f);
}

// Round 18
// 549.853 us; speedup vs baseline: 1.0151x; 1.0151x over previous
//
#include <hip/hip_runtime.h>
#include <hip/hip_bf16.h>
#include <stdint.h>

#define S_LEN  2048
#define NHEADS 16
#define D_NOPE 128
#define D_ROPE 64
#define D_V    128
#define D_Q    192
#define ITOPK  512

static constexpr float ATT_SCALE = 0.07216878364870322f;   // 192^-0.5
static constexpr float ISC4      = 0.04419417382415922f;   // (32^-0.5)/4
static constexpr float RMS_EPS   = 1e-6f;

typedef __bf16 bf16x8 __attribute__((ext_vector_type(8)));
typedef float  f32x4  __attribute__((ext_vector_type(4)));

__device__ __forceinline__ float b2f(unsigned short u) {
    union { unsigned int i; float f; } x; x.i = ((unsigned int)u) << 16; return x.f;
}
__device__ __forceinline__ unsigned short f2b(float f) {   // RNE
    union { float f; unsigned int i; } x; x.f = f;
    unsigned int lsb = (x.i >> 16) & 1;
    x.i += 0x7fffu + lsb;
    return (unsigned short)(x.i >> 16);
}

// async global->LDS, 16B per lane; LDS dest must be wave-uniform base + lane*16
__device__ __forceinline__ void gload16(const unsigned short* g, unsigned short* l)
{
    __builtin_amdgcn_global_load_lds(
        (const __attribute__((address_space(1))) unsigned int*)g,
        (__attribute__((address_space(3))) unsigned int*)l, 16, 0, 0);
}

// ---------------- fused f32 -> bf16 casts (6 segments, TOTAL 4,882,432 float4) ----------------
__global__ __launch_bounds__(256)
void cast_all(const float* __restrict__ x,    const float* __restrict__ qaw_,
              const float* __restrict__ kvaw_, const float* __restrict__ qbw_,
              const float* __restrict__ kvbw_, const float* __restrict__ ow_,
              unsigned short* __restrict__ xb,   unsigned short* __restrict__ wcat,
              unsigned short* __restrict__ qbw,  unsigned short* __restrict__ kvbw,
              unsigned short* __restrict__ owb)
{
    int i = blockIdx.x * 256 + threadIdx.x;   // float4 index
    const float* s; unsigned short* d; int off;
    if      (i < 1048576) { s = x;     d = xb;              off = 0;       }
    else if (i < 1835008) { s = qaw_;  d = wcat;            off = 1048576; }
    else if (i < 2129920) { s = kvaw_; d = wcat + 3145728;  off = 1835008; }
    else if (i < 3309568) { s = qbw_;  d = qbw;             off = 2129920; }
    else if (i < 3833856) { s = kvbw_; d = kvbw;            off = 3309568; }
    else if (i < 4882432) { s = ow_;   d = owb;             off = 3833856; }
    else return;
    int j = i - off;
    float4 v = ((const float4*)s)[j];
    ushort4 o;
    o.x = f2b(v.x); o.y = f2b(v.y); o.z = f2b(v.z); o.w = f2b(v.w);
    ((ushort4*)d)[j] = o;
}

// ---------------- f32 VALU GEMM, BK=16, dual-B (indexer iq|ik; ROUND-10-EXACT math) ----
__global__ __launch_bounds__(256)
void gemm_f32_iqik(const float* __restrict__ A, int lda,
                   const float* __restrict__ Bq, const float* __restrict__ Bk,
                   float* __restrict__ C, int M, float alpha, int kChunk)
{
    __shared__ float As[16][132];
    __shared__ float Bs[16][132];
    const int row0 = blockIdx.y * 128;
    const int col0 = blockIdx.x * 128;
    const int t  = threadIdx.x;
    const int tx = t & 15, ty = t >> 4;
    const int kStart = blockIdx.z * kChunk;
    C += (size_t)blockIdx.z * M * 256;

    float acc[8][8] = {};

    for (int k0 = kStart; k0 < kStart + kChunk; k0 += 16) {
#pragma unroll
        for (int i = 0; i < 2; i++) {
            int f = t + i * 256;
            int r = f >> 2;
            int kq = (f & 3) << 2;
            int gr = row0 + r;
            float4 va = make_float4(0.f, 0.f, 0.f, 0.f);
            if (gr < M) va = *(const float4*)(A + (size_t)gr * lda + k0 + kq);
            As[kq + 0][r] = va.x; As[kq + 1][r] = va.y;
            As[kq + 2][r] = va.z; As[kq + 3][r] = va.w;
            int gc = col0 + r;    // 0..255
            const float* bp = (gc < 128) ? (Bq + (size_t)gc * 2048)
                                         : (Bk + (size_t)(gc - 128) * 2048);
            float4 vb = *(const float4*)(bp + k0 + kq);
            Bs[kq + 0][r] = vb.x; Bs[kq + 1][r] = vb.y;
            Bs[kq + 2][r] = vb.z; Bs[kq + 3][r] = vb.w;
        }
        __syncthreads();
#pragma unroll
        for (int kk = 0; kk < 16; kk++) {
            float4 A0 = *(const float4*)&As[kk][ty * 8];
            float4 A1 = *(const float4*)&As[kk][ty * 8 + 4];
            float4 B0 = *(const float4*)&Bs[kk][tx * 8];
            float4 B1 = *(const float4*)&Bs[kk][tx * 8 + 4];
            float a[8] = {A0.x, A0.y, A0.z, A0.w, A1.x, A1.y, A1.z, A1.w};
            float b[8] = {B0.x, B0.y, B0.z, B0.w, B1.x, B1.y, B1.z, B1.w};
#pragma unroll
            for (int i = 0; i < 8; i++)
#pragma unroll
                for (int j = 0; j < 8; j++)
                    acc[i][j] = fmaf(a[i], b[j], acc[i][j]);
        }
        __syncthreads();
    }

#pragma unroll
    for (int i = 0; i < 8; i++) {
        int r = row0 + ty * 8 + i;
        if (r >= M) continue;
#pragma unroll
        for (int j = 0; j < 8; j++) {
            int c = col0 + tx * 8 + j;
            C[(size_t)r * 256 + c] = acc[i][j] * alpha;
        }
    }
}

// ---------------- f32 VALU GEMM, BK=16, strided A/B (isc; ROUND-10 EXACT) ----
__global__ __launch_bounds__(256)
void gemm_f32_nt(const float* __restrict__ A, int lda,
                 const float* __restrict__ B, int ldb,
                 float* __restrict__ C, int M, int N, float alpha, int kChunk)
{
    __shared__ float As[16][132];
    __shared__ float Bs[16][132];
    const int row0 = blockIdx.y * 128;
    const int col0 = blockIdx.x * 128;
    const int t  = threadIdx.x;
    const int tx = t & 15, ty = t >> 4;
    const int kStart = blockIdx.z * kChunk;
    C += (size_t)blockIdx.z * M * N;

    float acc[8][8] = {};

    for (int k0 = kStart; k0 < kStart + kChunk; k0 += 16) {
#pragma unroll
        for (int i = 0; i < 2; i++) {
            int f = t + i * 256;
            int r = f >> 2;
            int kq = (f & 3) << 2;
            int gr = row0 + r;
            float4 va = make_float4(0.f, 0.f, 0.f, 0.f);
            if (gr < M) va = *(const float4*)(A + (size_t)gr * lda + k0 + kq);
            As[kq + 0][r] = va.x; As[kq + 1][r] = va.y;
            As[kq + 2][r] = va.z; As[kq + 3][r] = va.w;
            int gc = col0 + r;
            float4 vb = make_float4(0.f, 0.f, 0.f, 0.f);
            if (gc < N) vb = *(const float4*)(B + (size_t)gc * ldb + k0 + kq);
            Bs[kq + 0][r] = vb.x; Bs[kq + 1][r] = vb.y;
            Bs[kq + 2][r] = vb.z; Bs[kq + 3][r] = vb.w;
        }
        __syncthreads();
#pragma unroll
        for (int kk = 0; kk < 16; kk++) {
            float4 A0 = *(const float4*)&As[kk][ty * 8];
            float4 A1 = *(const float4*)&As[kk][ty * 8 + 4];
            float4 B0 = *(const float4*)&Bs[kk][tx * 8];
            float4 B1 = *(const float4*)&Bs[kk][tx * 8 + 4];
            float a[8] = {A0.x, A0.y, A0.z, A0.w, A1.x, A1.y, A1.z, A1.w};
            float b[8] = {B0.x, B0.y, B0.z, B0.w, B1.x, B1.y, B1.z, B1.w};
#pragma unroll
            for (int i = 0; i < 8; i++)
#pragma unroll
                for (int j = 0; j < 8; j++)
                    acc[i][j] = fmaf(a[i], b[j], acc[i][j]);
        }
        __syncthreads();
    }

#pragma unroll
    for (int i = 0; i < 8; i++) {
        int r = row0 + ty * 8 + i;
        if (r >= M) continue;
#pragma unroll
        for (int j = 0; j < 8; j++) {
            int c = col0 + tx * 8 + j;
            if (c >= N) continue;
            C[(size_t)r * N + c] = acc[i][j] * alpha;
        }
    }
}

// ---------------- reduce P split-K partials (in-place over slab 0 safe) ----------------
__global__ __launch_bounds__(256)
void reduceN_k(const float* __restrict__ p, float* __restrict__ out, int n4, int parts)
{
    int i = blockIdx.x * 256 + threadIdx.x;
    if (i < n4) {
        const float4* a = (const float4*)p;
        float4 o = a[i];
        for (int z = 1; z < parts; z++) {
            float4 r = a[i + (size_t)z * n4];
            o.x += r.x; o.y += r.y; o.z += r.z; o.w += r.w;
        }
        ((float4*)out)[i] = o;
    }
}

// ---------------- bf16 MFMA GEMM, strided + per-z stepped ----------------
template<bool OUTBF16>
__global__ __launch_bounds__(256)
void gemm_bf16_nt(const unsigned short* __restrict__ A, int lda, int aStep,
                  const unsigned short* __restrict__ B, int ldb, int bStep,
                  void* __restrict__ Cv, int ldc, int cStep,
                  int M, int N, int K, float alpha)
{
    __shared__ unsigned short As[128 * 32];
    __shared__ unsigned short Bs[128 * 32];
    A += (size_t)blockIdx.z * aStep;
    B += (size_t)blockIdx.z * bStep;
    unsigned short* Cb = (unsigned short*)Cv + (size_t)blockIdx.z * cStep;
    float*          Cf = (float*)Cv          + (size_t)blockIdx.z * cStep;

    const int t = threadIdx.x;
    const int row0 = blockIdx.y * 128, col0 = blockIdx.x * 128;
    const int w = t >> 6, l = t & 63;
    const int wr = (w >> 1) * 64, wc = (w & 1) * 64;
    const int fr = l & 15, fk = l >> 4;

    f32x4 acc[4][4] = {};

    const int sr = t >> 2, ss = t & 3;

    for (int k0 = 0; k0 < K; k0 += 32) {
#pragma unroll
        for (int c = 0; c < 2; c++) {
            int r  = sr + c * 64;
            int ga = min(row0 + r, M - 1);
            int gb = min(col0 + r, N - 1);
            gload16(A + (size_t)ga * lda + k0 + ss * 8, As + (c * 256 + t) * 8);
            gload16(B + (size_t)gb * ldb + k0 + ss * 8, Bs + (c * 256 + t) * 8);
        }
        __syncthreads();

        bf16x8 af[4], bfr[4];
#pragma unroll
        for (int mi = 0; mi < 4; mi++) {
            int ra = wr + mi * 16 + fr;
            af[mi] = *(const bf16x8*)((const char*)As + ra * 64 + fk * 16);
        }
#pragma unroll
        for (int nj = 0; nj < 4; nj++) {
            int rb = wc + nj * 16 + fr;
            bfr[nj] = *(const bf16x8*)((const char*)Bs + rb * 64 + fk * 16);
        }
#pragma unroll
        for (int mi = 0; mi < 4; mi++)
#pragma unroll
            for (int nj = 0; nj < 4; nj++)
                acc[mi][nj] = __builtin_amdgcn_mfma_f32_16x16x32_bf16(
                                  af[mi], bfr[nj], acc[mi][nj], 0, 0, 0);
        __syncthreads();
    }

    // C/D: col = lane&15, row = (lane>>4)*4 + reg
#pragma unroll
    for (int mi = 0; mi < 4; mi++)
#pragma unroll
        for (int nj = 0; nj < 4; nj++)
#pragma unroll
            for (int rg = 0; rg < 4; rg++) {
                int rr = row0 + wr + mi * 16 + fk * 4 + rg;
                int cc = col0 + wc + nj * 16 + fr;
                if (rr < M && cc < N) {
                    float v = acc[mi][nj][rg] * alpha;
                    if constexpr (OUTBF16) Cb[(size_t)rr * ldc + cc] = f2b(v);
                    else                   Cf[(size_t)rr * ldc + cc] = v;
                }
            }
}

// ---------------- RMSNorm bf16 in-place (strided rows) ----------------
__global__ __launch_bounds__(256)
void rms_bf16_inplace(unsigned short* x, const float* __restrict__ w, int n, int stride)
{
    __shared__ float red[256];
    const int row = blockIdx.x, t = threadIdx.x;
    unsigned short* ip = x + (size_t)row * stride;
    float ss = 0.f;
    for (int i = t; i < n; i += 256) { float v = b2f(ip[i]); ss = fmaf(v, v, ss); }
    red[t] = ss; __syncthreads();
    for (int s2 = 128; s2; s2 >>= 1) { if (t < s2) red[t] += red[t + s2]; __syncthreads(); }
    float rs = rsqrtf(red[0] / (float)n + RMS_EPS);
    for (int i = t; i < n; i += 256) ip[i] = f2b(b2f(ip[i]) * rs * w[i]);
}

// ---------------- fused RMS(ckv) + RoPE(k_pe): xa[row][1536..2111] -> klat[row][0..575] ----
__global__ __launch_bounds__(256)
void rmsrope_klat(const unsigned short* __restrict__ xa, const float* __restrict__ w,
                  const float* __restrict__ cosb, const float* __restrict__ sinb,
                  unsigned short* __restrict__ klat)
{
    __shared__ float red[256];
    const int row = blockIdx.x, t = threadIdx.x;
    const unsigned short* ip = xa + (size_t)row * 2112 + 1536;   // 512 ckv | 64 kpe
    float v0 = b2f(ip[t]), v1 = b2f(ip[t + 256]);
    red[t] = v0 * v0 + v1 * v1; __syncthreads();
    for (int s2 = 128; s2; s2 >>= 1) { if (t < s2) red[t] += red[t + s2]; __syncthreads(); }
    float rs = rsqrtf(red[0] / 512.f + RMS_EPS);
    unsigned short* op = klat + (size_t)row * 576;
    op[t]       = f2b(v0 * rs * w[t]);
    op[t + 256] = f2b(v1 * rs * w[t + 256]);
    if (t < 32) {
        int d = t;
        float x1 = b2f(ip[512 + d]), x2 = b2f(ip[512 + d + 32]);
        const float* cr = cosb + (size_t)row * D_ROPE;
        const float* sr = sinb + (size_t)row * D_ROPE;
        op[512 + d]      = f2b(x1 * cr[d]      - x2 * sr[d]);
        op[512 + d + 32] = f2b(x2 * cr[d + 32] + x1 * sr[d + 32]);
    }
}

// ---------------- RoPE q_pe: qbuf[S][16][192] dims 128.. -> qec[S][16][576] dims 512.. ----
__global__ __launch_bounds__(256)
void rope_q_k(const unsigned short* __restrict__ qbuf, const float* __restrict__ cosb,
              const float* __restrict__ sinb, unsigned short* __restrict__ qec)
{
    int idx = blockIdx.x * 256 + threadIdx.x;  // S*16*32
    int s = idx >> 9, h = (idx >> 5) & 15, d = idx & 31;
    const unsigned short* qp = qbuf + ((size_t)s * NHEADS + h) * D_Q + D_NOPE;
    float x1 = b2f(qp[d]), x2 = b2f(qp[d + 32]);
    const float* cr = cosb + (size_t)s * D_ROPE;
    const float* sr = sinb + (size_t)s * D_ROPE;
    unsigned short* op = qec + ((size_t)s * NHEADS + h) * 576 + 512;
    op[d]      = f2b(x1 * cr[d]      - x2 * sr[d]);
    op[d + 32] = f2b(x2 * cr[d + 32] + x1 * sr[d + 32]);
}

// ---------------- transpose W_kb (k_nope half): Wkt[h][c<512][d<128] ----------------
__global__ __launch_bounds__(256)
void wkt_k(const unsigned short* __restrict__ kvbw, unsigned short* __restrict__ wkt)
{
    __shared__ unsigned short tile[32][520];
    const int h = blockIdx.x, dc = blockIdx.y, t = threadIdx.x;
    for (int i = t; i < 32 * 64; i += 256) {
        int d = i >> 6, c8 = (i & 63) * 8;
        uint4 v = *(const uint4*)(kvbw + ((size_t)(h * 256 + dc * 32 + d)) * 512 + c8);
        *(uint4*)&tile[d][c8] = v;
    }
    __syncthreads();
    for (int i = t; i < 512 * 4; i += 256) {
        int c = i >> 2, d8 = (i & 3) * 8;
        unsigned short tmp[8];
#pragma unroll
        for (int j = 0; j < 8; j++) tmp[j] = tile[d8 + j][c];
        *(uint4*)(wkt + ((size_t)h * 512 + c) * 128 + dc * 32 + d8) = *(uint4*)tmp;
    }
}

// ---------------- ckv column means (empty-mask fallback) ----------------
__global__ __launch_bounds__(256)
void ckvsum_k(const unsigned short* __restrict__ klat, float* __restrict__ part)
{
    const int b = blockIdx.x, t = threadIdx.x;
    float s0 = 0.f, s1 = 0.f;
    for (int r = 0; r < 128; r++) {
        const unsigned short* row = klat + (size_t)(b * 128 + r) * 576;
        s0 += b2f(row[t]); s1 += b2f(row[t + 256]);
    }
    part[b * 512 + t] = s0; part[b * 512 + t + 256] = s1;
}
__global__ __launch_bounds__(256)
void ckvmean_k(const float* __restrict__ part, float* __restrict__ mean)
{
    int t = blockIdx.x * 256 + threadIdx.x;
    if (t < 512) {
        float s = 0.f;
        for (int b = 0; b < 16; b++) s += part[b * 512 + t];
        mean[t] = s * (1.f / 2048.f);
    }
}

// ---------------- per-row top-512 -> bitmask, 4-pass byte radix-select ----------------
__global__ __launch_bounds__(256)
void topk_mask_k(const float* __restrict__ iscores, uint32_t* __restrict__ mask)
{
    const int q = blockIdx.x, t = threadIdx.x;
    const int w = t >> 6, l = t & 63;
    __shared__ uint32_t u[S_LEN];
    __shared__ int hist4[4][256];
    __shared__ int sfx[257];
    __shared__ int wtot[4];
    __shared__ uint32_t mw[64];
    __shared__ int sh_b, sh_R;

    for (int i = t; i < S_LEN; i += 256) {
        uint32_t b = __float_as_uint(iscores[(size_t)q * S_LEN + i]);
        u[i] = (b & 0x80000000u) ? ~b : (b | 0x80000000u);  // order-preserving map
    }
    if (t < 64) mw[t] = 0u;

    uint32_t prefix = 0;
    int R = ITOPK;
#pragma unroll 1
    for (int shift = 24; shift >= 0; shift -= 8) {
        hist4[0][t] = 0; hist4[1][t] = 0; hist4[2][t] = 0; hist4[3][t] = 0;
        __syncthreads();
        uint32_t pmask = (shift == 24) ? 0u : (0xFFFFFFFFu << (shift + 8));
        for (int i = t; i < S_LEN; i += 256) {
            uint32_t v = u[i];
            if ((v & pmask) == prefix)
                atomicAdd(&hist4[w][(v >> shift) & 255], 1);
        }
        __syncthreads();
        int x = hist4[0][255 - t] + hist4[1][255 - t] + hist4[2][255 - t] + hist4[3][255 - t];
#pragma unroll
        for (int d = 1; d < 64; d <<= 1) {
            int y = __shfl_up(x, d);
            if (l >= d) x += y;
        }
        if (l == 63) wtot[w] = x;
        __syncthreads();
        for (int ww = 0; ww < w; ww++) x += wtot[ww];
        sfx[255 - t] = x;
        if (t == 0) sfx[256] = 0;
        __syncthreads();
        if (sfx[t] >= R && sfx[t + 1] < R) { sh_b = t; sh_R = R - sfx[t + 1]; }
        __syncthreads();
        prefix |= (uint32_t)sh_b << shift;
        R = sh_R;
        __syncthreads();
    }
    const uint32_t T = prefix;
    const int need = R;

    for (int i = t; i < S_LEN; i += 256) {
        uint32_t v = u[i];
        bool sel = v > T;
        if (!sel && v == T) {
            int rank = 0;
            for (int j = 0; j < i; j++) rank += (u[j] == T) ? 1 : 0;
            sel = rank < need;
        }
        if (sel) atomicOr(&mw[i >> 5], 1u << (i & 31));
    }
    __syncthreads();
    if (t < 64) mask[(size_t)q * 64 + t] = mw[t];
}

// ---------------- absorbed-MLA sparse attention: one block per q, all 16 heads ----
// ROUND-16 PROVEN CONFIG: half-lat CT (39.4KB, 4 blocks/CU), natural qi order.
// (r15 tail-remap: -34% L2 locality; r17 quarter-lat/5 blocks: barrier cost > occupancy gain.)
__global__ __launch_bounds__(256, 4)
void attn_lat_k(const unsigned short* __restrict__ qec,
                const unsigned short* __restrict__ klat,
                const uint32_t* __restrict__ mask,
                const float* __restrict__ ckvmean,
                unsigned short* __restrict__ ov)
{
    const int qi = blockIdx.x, t = threadIdx.x;
    const int w = t >> 6, l = t & 63;
    const int c16 = l & 15, g = l >> 4;

    __shared__ unsigned short kl[512];
    __shared__ uint32_t wds[64];
    __shared__ int pfx[65];
    __shared__ float wred[4][16];
    __shared__ float linv[16];
    __shared__ unsigned short PB[16][520];   // P (unnormalized exp) bf16
    __shared__ unsigned short CT[256][40];   // ckv_sel^T half-lat tile, swizzled cols

    kl[t] = 0; kl[t + 256] = 0;
    if (t < 64) {
        uint32_t wd = mask[(size_t)qi * 64 + t];
        int rem = qi - t * 32;                 // causal
        if (rem < 0) wd = 0u;
        else if (rem < 31) wd &= ((2u << rem) - 1u);
        wds[t] = wd;
        pfx[t] = __popc(wd);
    }
    __syncthreads();
    if (t == 0) {
        int s = 0;
        for (int i = 0; i < 64; i++) { int cc = pfx[i]; pfx[i] = s; s += cc; }
        pfx[64] = s;
    }
    __syncthreads();
    const int nv = pfx[64];

    if (nv == 0) {   // uniform softmax over all keys == mean(ckv) in latent space
        for (int i = t; i < 16 * 512; i += 256) {
            int h = i >> 9, c = i & 511;
            ov[((size_t)qi * 16 + h) * 512 + c] = f2b(ckvmean[c]);
        }
        return;
    }

    if (t < 64) {
        int pos = pfx[t];
        uint32_t wd = wds[t];
        while (wd) { int b = __ffs(wd) - 1; wd &= wd - 1; kl[pos++] = (unsigned short)(t * 32 + b); }
    }
    __syncthreads();

    const int ntile = (nv + 63) >> 6;   // 64-key macro tiles (4 waves x 16)

    // ---- scores: S[h=16][key] = Qec[16x576] @ Klat_sel^T via MFMA ----
    f32x4 acc[8] = {};
    uint32_t kb[8];
#pragma unroll
    for (int tt = 0; tt < 8; tt++)
        kb[tt] = (uint32_t)kl[tt * 64 + w * 16 + c16] * 1152u;

    const unsigned short* qrow = qec + (size_t)qi * (16 * 576);
#pragma unroll 2
    for (int ks = 0; ks < 18; ks++) {
        bf16x8 af = *(const bf16x8*)(qrow + c16 * 576 + ks * 32 + g * 8);
#pragma unroll
        for (int tt = 0; tt < 8; tt++) {
            if (tt < ntile) {
                bf16x8 bf = *(const bf16x8*)((const char*)klat + (kb[tt] + (uint32_t)(ks * 64 + g * 16)));
                acc[tt] = __builtin_amdgcn_mfma_f32_16x16x32_bf16(af, bf, acc[tt], 0, 0, 0);
            }
        }
    }

    // scale + pad-mask + per-head max
    float m4[4];
#pragma unroll
    for (int r = 0; r < 4; r++) {
        float mm = -1e30f;
#pragma unroll
        for (int tt = 0; tt < 8; tt++) {
            if (tt < ntile) {
                int kp = tt * 64 + w * 16 + c16;
                float s = (kp < nv) ? acc[tt][r] * ATT_SCALE : -1e30f;
                acc[tt][r] = s;
                mm = fmaxf(mm, s);
            }
        }
#pragma unroll
        for (int o = 8; o; o >>= 1) mm = fmaxf(mm, __shfl_xor(mm, o));
        m4[r] = mm;
    }
    if (c16 == 0) {
#pragma unroll
        for (int r = 0; r < 4; r++) wred[w][g * 4 + r] = m4[r];
    }
    __syncthreads();
#pragma unroll
    for (int r = 0; r < 4; r++) {
        int h = g * 4 + r;
        m4[r] = fmaxf(fmaxf(wred[0][h], wred[1][h]), fmaxf(wred[2][h], wred[3][h]));
    }
    __syncthreads();   // wred reused for sums

    float s4[4] = {0.f, 0.f, 0.f, 0.f};
#pragma unroll
    for (int tt = 0; tt < 8; tt++) {
        if (tt < ntile) {
            int kp = tt * 64 + w * 16 + c16;
#pragma unroll
            for (int r = 0; r < 4; r++) {
                float e = __expf(acc[tt][r] - m4[r]);   // pad keys -> 0
                s4[r] += e;
                PB[g * 4 + r][kp] = f2b(e);
            }
        }
    }
#pragma unroll
    for (int r = 0; r < 4; r++) {
        float ss = s4[r];
#pragma unroll
        for (int o = 8; o; o >>= 1) ss += __shfl_xor(ss, o);
        s4[r] = ss;
    }
    if (c16 == 0) {
#pragma unroll
        for (int r = 0; r < 4; r++) wred[w][g * 4 + r] = s4[r];
    }
    __syncthreads();
    if (t < 16) linv[t] = 1.f / (wred[0][t] + wred[1][t] + wred[2][t] + wred[3][t]);

    // ---- PV: ov[16][512] = P[16 x nv] @ ckv_sel[nv x 512], lat-halved CT ----
    f32x4 pv[8] = {};
    const int nkc = (nv + 31) >> 5;
    const int k2 = t >> 4, lg = t & 15;
    const int cp = (k2 ^ ((lg & 3) << 2)) * 2;   // u16 column of this thread's key pair
    uint4 stg[4];

#define LOADKEYS(HT, KC) do { \
        uint32_t kb0 = (uint32_t)kl[(KC) * 32 + 2 * k2] * 1152u; \
        uint32_t kb1 = (uint32_t)kl[(KC) * 32 + 2 * k2 + 1] * 1152u; \
        const uint4* s0 = (const uint4*)((const char*)klat + kb0 + (HT) * 512 + lg * 32); \
        const uint4* s1 = (const uint4*)((const char*)klat + kb1 + (HT) * 512 + lg * 32); \
        stg[0] = s0[0]; stg[1] = s0[1]; stg[2] = s1[0]; stg[3] = s1[1]; \
    } while (0)

    LOADKEYS(0, 0);
#pragma unroll
    for (int ht = 0; ht < 2; ht++) {
        for (int kc = 0; kc < nkc; kc++) {
            __syncthreads();     // prev MFMA done with CT; first iter publishes PB/linv
            {
#pragma unroll
                for (int v4 = 0; v4 < 2; v4++) {
                    uint4 a4 = stg[v4], b4 = stg[v4 + 2];
                    int la = lg * 16 + v4 * 8;
                    *(uint32_t*)&CT[la + 0][cp] = (a4.x & 0xFFFFu) | (b4.x << 16);
                    *(uint32_t*)&CT[la + 1][cp] = (a4.x >> 16) | (b4.x & 0xFFFF0000u);
                    *(uint32_t*)&CT[la + 2][cp] = (a4.y & 0xFFFFu) | (b4.y << 16);
                    *(uint32_t*)&CT[la + 3][cp] = (a4.y >> 16) | (b4.y & 0xFFFF0000u);
                    *(uint32_t*)&CT[la + 4][cp] = (a4.z & 0xFFFFu) | (b4.z << 16);
                    *(uint32_t*)&CT[la + 5][cp] = (a4.z >> 16) | (b4.z & 0xFFFF0000u);
                    *(uint32_t*)&CT[la + 6][cp] = (a4.w & 0xFFFFu) | (b4.w << 16);
                    *(uint32_t*)&CT[la + 7][cp] = (a4.w >> 16) | (b4.w & 0xFFFF0000u);
                }
            }
            if (kc + 1 < nkc) LOADKEYS(ht, kc + 1);      // fly under this chunk's MFMAs
            else if (ht == 0) LOADKEYS(1, 0);
            __syncthreads();
            bf16x8 pa = *(const bf16x8*)(&PB[c16][kc * 32 + g * 8]);
            __builtin_amdgcn_s_setprio(1);
#pragma unroll
            for (int nt = 0; nt < 4; nt++) {
                int rowh = w * 64 + nt * 16 + c16;
                bf16x8 cb = *(const bf16x8*)(&CT[rowh][(g ^ nt) * 8]);
                pv[ht * 4 + nt] = __builtin_amdgcn_mfma_f32_16x16x32_bf16(
                                      pa, cb, pv[ht * 4 + nt], 0, 0, 0);
            }
            __builtin_amdgcn_s_setprio(0);
        }
    }
#undef LOADKEYS

#pragma unroll
    for (int ht = 0; ht < 2; ht++)
#pragma unroll
        for (int nt = 0; nt < 4; nt++)
#pragma unroll
            for (int r = 0; r < 4; r++) {
                int h = g * 4 + r;
                int lat = ht * 256 + w * 64 + nt * 16 + c16;
                ov[((size_t)qi * 16 + h) * 512 + lat] = f2b(pv[ht * 4 + nt][r] * linv[h]);
            }
}

// ---------------- launch ----------------
extern "C" void kernel_launch(void* const* d_in, const int* in_sizes, int n_in,
                              void* d_out, int out_size, void* d_ws, size_t ws_size,
                              hipStream_t stream)
{
    const float* x       = (const float*)d_in[0];
    const float* cosb    = (const float*)d_in[1];
    const float* sinb    = (const float*)d_in[2];
    const float* q_a_w   = (const float*)d_in[3];
    const float* q_a_nw  = (const float*)d_in[4];
    const float* q_b_w   = (const float*)d_in[5];
    const float* kv_a_w  = (const float*)d_in[6];
    const float* kv_a_nw = (const float*)d_in[7];
    const float* kv_b_w  = (const float*)d_in[8];
    const float* o_w     = (const float*)d_in[9];
    const float* idx_q_w = (const float*)d_in[10];
    const float* idx_k_w = (const float*)d_in[11];
    (void)in_sizes; (void)n_in; (void)out_size; (void)ws_size;

    typedef unsigned short u16;
    char* ws = (char*)d_ws;
    // region A (overlaid by qec after step 5 — qec LIVE through step 8)
    u16*      xb   = (u16*)(ws + 0);          //  8,388,608 x bf16
    u16*      wcat = (u16*)(ws + 8388608);    //  8,650,752 [2112][2048] q_a_w|kv_a_w bf16
    u16*      qbw  = (u16*)(ws + 17039360);   //  9,437,184 q_b_w bf16
    u16*      xa   = (u16*)(ws + 26476544);   //  8,650,752 [2048][2112] q_a|ckv|kpe bf16
    u16*      qec  = (u16*)(ws + 0);          // 37,748,736 [S][16][576] (overlay, steps 5-8)
    // region B (33.5MB): wkt -> ipc/iqik/isc -> ov
    u16*      wkt  = (u16*)(ws + 37748736);   //  2,097,152 W_kb^T per head [steps 4-5]
    float*    ipc  = (float*)(ws + 37748736); // 16,777,216 idx partials x8 [step 7]
    float*    iqik = (float*)(ws + 37748736); //  2,097,152 [2048][256] (in-place reduce, slab 0)
    float*    isc  = (float*)(ws + 39845888); // 16,777,216 iscores (overlaps dead ipc slabs 1-7)
    u16*      ov   = (u16*)(ws + 37748736);   // 33,554,432 [S][16][512] (overlay, step 8+)
    // region C
    u16*      qbuf = (u16*)(ws + 71303168);   // 12,582,912 q bf16 (dead after step 5)
    u16*      aoutb= (u16*)(ws + 71303168);   //  8,388,608 attn out (overlay, step 9+)
    u16*      klat = (u16*)(ws + 83886080);   //  2,359,296 [S][576] latent K
    u16*      kvbw = (u16*)(ws + 86245376);   //  4,194,304 kv_b_w bf16
    u16*      owb  = (u16*)(ws + 90439680);   //  8,388,608 o_w bf16
    uint32_t* mask = (uint32_t*)(ws + 98828288); // 524,288
    float*    ckvm = (float*)(ws + 99352576); //      2,048
    float*    cprt = (float*)(ws + 99354624); //     32,768  (end 99,387,392)

    dim3 blk(256);

    // 1. all casts fused — grid covers 4,882,432 float4 exactly
    cast_all<<<19072, blk, 0, stream>>>(x, q_a_w, kv_a_w, q_b_w, kv_b_w, o_w,
                                        xb, wcat, qbw, kvbw, owb);

    // 2. fused low-rank projection: xa[2048][2112] = xb @ wcat^T
    gemm_bf16_nt<true ><<<dim3(17, 16), blk, 0, stream>>>(xb, 2048, 0, wcat, 2048, 0,
                                                          xa, 2112, 0, 2048, 2112, 2048, 1.f);
    // 3. norms + k rope (q_a in-place; ckv+kpe -> klat)
    rms_bf16_inplace<<<2048, blk, 0, stream>>>(xa, q_a_nw, 1536, 2112);
    rmsrope_klat<<<2048, blk, 0, stream>>>(xa, kv_a_nw, cosb, sinb, klat);

    // 4. q_b projection + W_kb transpose
    gemm_bf16_nt<true ><<<dim3(24, 16), blk, 0, stream>>>(xa, 2112, 0, qbw, 1536, 0,
                                                          qbuf, 3072, 0, 2048, 3072, 1536, 1.f);
    wkt_k<<<dim3(16, 4), blk, 0, stream>>>(kvbw, wkt);

    // 5. absorbed q: qec[:,:,0:512] = q_nope @ W_kb^T; qec[:,:,512:576] = rope(q_pe)
    gemm_bf16_nt<true ><<<dim3(4, 16, 16), blk, 0, stream>>>(qbuf, 3072, 192, wkt, 128, 512 * 128,
                                                             qec, 9216, 576, 2048, 512, 128, 1.f);
    rope_q_k<<<4096, blk, 0, stream>>>(qbuf, cosb, sinb, qec);

    // 6. latent mean (fallback rows)
    ckvsum_k<<<16, blk, 0, stream>>>(klat, cprt);
    ckvmean_k<<<2, blk, 0, stream>>>(cprt, ckvm);

    // 7. indexer — ROUND-10-EXACT math (BK=16, kChunk=256, z=8); dual-B
    gemm_f32_iqik<<<dim3(2, 16, 8), blk, 0, stream>>>(x, 2048, idx_q_w, idx_k_w,
                                                      ipc, 2048, 1.f, 256);
    reduceN_k<<<512, blk, 0, stream>>>(ipc, iqik, 131072, 8);
    gemm_f32_nt<<<dim3(16, 16, 1), blk, 0, stream>>>(iqik, 256, iqik + 128, 256,
                                                     isc, 2048, 2048, ISC4, 128);
    topk_mask_k<<<2048, blk, 0, stream>>>(isc, mask);

    // 8. absorbed sparse attention (natural qi order, 4 blocks/CU)
    attn_lat_k<<<2048, blk, 0, stream>>>(qec, klat, mask, ckvm, ov);

    // 9. un-absorb values: aout[q][h*128+d] = ov[q][h] . W_vb[h][d]
    gemm_bf16_nt<true ><<<dim3(1, 16, 16), blk, 0, stream>>>(ov, 8192, 512,
                                                             kvbw + 128 * 512, 512, 256 * 512,
                                                             aoutb, 2048, 128, 2048, 128, 512, 1.f);
    // 10. output projection (f32 out)
    gemm_bf16_nt<false><<<dim3(16, 16), blk, 0, stream>>>(aoutb, 2048, 0, owb, 2048, 0,
                                                          (float*)d_out, 2048, 0, 2048, 2048, 2048, 1.f);
}